// Round 1
// baseline (653.456 us; speedup 1.0000x reference)
//
#include <hip/hip_runtime.h>
#include <hip/hip_bf16.h>

// Problem constants
#define BB 16
#define TT 1024
#define DD 256
#define NE 512
#define BT 16384   // BB*TT

// ---------------------------------------------------------------------------
// Row-wise L2 normalize: out[r] = in[r] / max(||in[r]||, 1e-12), cols == 256
// One block (256 threads) per row.
// ---------------------------------------------------------------------------
__global__ __launch_bounds__(256) void l2norm_rows(const float* __restrict__ in,
                                                   float* __restrict__ out) {
    const int row = blockIdx.x;
    const long long base = (long long)row * DD;
    const int t = threadIdx.x;
    float v = in[base + t];
    float ss = v * v;
    #pragma unroll
    for (int off = 32; off > 0; off >>= 1) ss += __shfl_down(ss, off, 64);
    __shared__ float partial[4];
    const int wave = t >> 6, lane = t & 63;
    if (lane == 0) partial[wave] = ss;
    __syncthreads();
    __shared__ float s_inv;
    if (t == 0) {
        float tot = partial[0] + partial[1] + partial[2] + partial[3];
        s_inv = 1.0f / fmaxf(sqrtf(tot), 1e-12f);
    }
    __syncthreads();
    out[base + t] = v * s_inv;
}

// ---------------------------------------------------------------------------
// Transpose [rows, cols] -> [cols, rows]  (tiny: 512x256)
// ---------------------------------------------------------------------------
__global__ void transpose_kern(const float* __restrict__ in, float* __restrict__ out,
                               int rows, int cols) {
    int idx = blockIdx.x * blockDim.x + threadIdx.x;
    if (idx < rows * cols) {
        int r = idx / cols, c = idx - r * cols;
        out[(long long)c * rows + r] = in[idx];
    }
}

// ---------------------------------------------------------------------------
// C[M,N] = A[M,K] * B[N,K]^T   (both row-major, row stride == K)
// 128x128 tile, BK=16, 256 threads, 8x8 micro-tile per thread.
// blockIdx.z = batch; sA/sB/sC are element batch strides.
// M,N divisible by 128; K divisible by 16. No bounds checks.
// ---------------------------------------------------------------------------
__global__ __launch_bounds__(256) void gemm_nt(const float* __restrict__ A,
                                               const float* __restrict__ Bm,
                                               float* __restrict__ C,
                                               int M, int N, int K,
                                               long long sA, long long sB, long long sC) {
    A  += sA * blockIdx.z;
    Bm += sB * blockIdx.z;
    C  += sC * blockIdx.z;
    const int bm = blockIdx.y * 128;
    const int bn = blockIdx.x * 128;

    __shared__ float As[16][132];   // [k][m], +4 pad
    __shared__ float Bs[16][132];   // [k][n]

    const int tid = threadIdx.x;
    const int tx = tid & 15;        // n-group
    const int ty = tid >> 4;        // m-group
    const int r  = tid >> 2;        // load row 0..63
    const int c4 = tid & 3;         // load float4-col 0..3

    float acc[8][8] = {};

    for (int k0 = 0; k0 < K; k0 += 16) {
        #pragma unroll
        for (int i = 0; i < 2; ++i) {
            const int rr = r + i * 64;
            float4 va = *(const float4*)(A + (long long)(bm + rr) * K + k0 + c4 * 4);
            As[c4 * 4 + 0][rr] = va.x;
            As[c4 * 4 + 1][rr] = va.y;
            As[c4 * 4 + 2][rr] = va.z;
            As[c4 * 4 + 3][rr] = va.w;
            float4 vb = *(const float4*)(Bm + (long long)(bn + rr) * K + k0 + c4 * 4);
            Bs[c4 * 4 + 0][rr] = vb.x;
            Bs[c4 * 4 + 1][rr] = vb.y;
            Bs[c4 * 4 + 2][rr] = vb.z;
            Bs[c4 * 4 + 3][rr] = vb.w;
        }
        __syncthreads();
        #pragma unroll
        for (int k = 0; k < 16; ++k) {
            float a[8], b[8];
            *(float4*)&a[0] = *(const float4*)&As[k][ty * 8];
            *(float4*)&a[4] = *(const float4*)&As[k][ty * 8 + 4];
            *(float4*)&b[0] = *(const float4*)&Bs[k][tx * 8];
            *(float4*)&b[4] = *(const float4*)&Bs[k][tx * 8 + 4];
            #pragma unroll
            for (int i = 0; i < 8; ++i)
                #pragma unroll
                for (int j = 0; j < 8; ++j)
                    acc[i][j] = fmaf(a[i], b[j], acc[i][j]);
        }
        __syncthreads();
    }

    #pragma unroll
    for (int i = 0; i < 8; ++i) {
        float* dst = C + (long long)(bm + ty * 8 + i) * N + bn + tx * 8;
        *(float4*)dst       = make_float4(acc[i][0], acc[i][1], acc[i][2], acc[i][3]);
        *(float4*)(dst + 4) = make_float4(acc[i][4], acc[i][5], acc[i][6], acc[i][7]);
    }
}

// ---------------------------------------------------------------------------
// Per row of score_ksh [BT, NE]: argmax (first occurrence, as float) and
// softmax weights. 256 threads, 2 cols each.
// ---------------------------------------------------------------------------
__global__ __launch_bounds__(256) void softmax_argmax(const float* __restrict__ S,
                                                      float* __restrict__ idx_out,
                                                      float* __restrict__ W) {
    const int row = blockIdx.x;
    const long long base = (long long)row * NE;
    const int t = threadIdx.x;
    const float v0 = S[base + t];
    const float v1 = S[base + t + 256];

    float bv; int bi;
    if (v1 > v0) { bv = v1; bi = t + 256; } else { bv = v0; bi = t; }
    #pragma unroll
    for (int off = 32; off > 0; off >>= 1) {
        float ov = __shfl_down(bv, off, 64);
        int   oi = __shfl_down(bi, off, 64);
        if (ov > bv || (ov == bv && oi < bi)) { bv = ov; bi = oi; }
    }
    __shared__ float pv[4];
    __shared__ int   pi[4];
    const int wave = t >> 6, lane = t & 63;
    if (lane == 0) { pv[wave] = bv; pi[wave] = bi; }
    __syncthreads();
    __shared__ float s_max;
    __shared__ int   s_idx;
    if (t == 0) {
        bv = pv[0]; bi = pi[0];
        #pragma unroll
        for (int k = 1; k < 4; ++k)
            if (pv[k] > bv || (pv[k] == bv && pi[k] < bi)) { bv = pv[k]; bi = pi[k]; }
        s_max = bv; s_idx = bi;
    }
    __syncthreads();
    const float m = s_max;
    const float e0 = expf(v0 - m);
    const float e1 = expf(v1 - m);
    float ssum = e0 + e1;
    #pragma unroll
    for (int off = 32; off > 0; off >>= 1) ssum += __shfl_down(ssum, off, 64);
    __shared__ float ps[4];
    if (lane == 0) ps[wave] = ssum;
    __syncthreads();
    __shared__ float s_sum;
    if (t == 0) s_sum = ps[0] + ps[1] + ps[2] + ps[3];
    __syncthreads();
    const float inv = 1.0f / s_sum;
    W[base + t]       = e0 * inv;
    W[base + t + 256] = e1 * inv;
    if (t == 0) idx_out[row] = (float)s_idx;
}

// ---------------------------------------------------------------------------
// Normalize raw vparams_w rows -> vpw out; gather vp_norm[idx] -> vph out.
// ---------------------------------------------------------------------------
__global__ __launch_bounds__(256) void vpw_finish(const float* __restrict__ raw,
                                                  const float* __restrict__ idxf,
                                                  const float* __restrict__ vp_norm,
                                                  float* __restrict__ vpw,
                                                  float* __restrict__ vph) {
    const int row = blockIdx.x;
    const long long base = (long long)row * DD;
    const int t = threadIdx.x;
    const float v = raw[base + t];
    float ss = v * v;
    #pragma unroll
    for (int off = 32; off > 0; off >>= 1) ss += __shfl_down(ss, off, 64);
    __shared__ float partial[4];
    const int wave = t >> 6, lane = t & 63;
    if (lane == 0) partial[wave] = ss;
    __syncthreads();
    __shared__ float s_inv;
    if (t == 0) {
        float tot = partial[0] + partial[1] + partial[2] + partial[3];
        s_inv = 1.0f / fmaxf(sqrtf(tot), 1e-12f);
    }
    __syncthreads();
    vpw[base + t] = v * s_inv;
    const int idx = (int)idxf[row];
    vph[base + t] = vp_norm[(long long)idx * DD + t];
}

// ---------------------------------------------------------------------------
extern "C" void kernel_launch(void* const* d_in, const int* in_sizes, int n_in,
                              void* d_out, int out_size, void* d_ws, size_t ws_size,
                              hipStream_t stream) {
    const float* key_soft = (const float*)d_in[0];   // [16,1024,256]
    const float* keys     = (const float*)d_in[1];   // [512,256]
    const float* vparams  = (const float*)d_in[2];   // [512,256]
    float* out = (float*)d_out;

    // Output layout (flat, return order)
    const long long off0 = 0;                    // encoding_indices [16384]
    const long long off1 = off0 + BT;            // vparams_w  [16384,256]
    const long long off2 = off1 + (long long)BT * DD;   // vparams_hard
    const long long off3 = off2 + (long long)BT * DD;   // score_vpss [16,1024,1024]
    const long long off4 = off3 + (long long)BB * TT * TT; // score_vpsh [16384,512]
    const long long off5 = off4 + (long long)BT * NE;   // score_kss [16,1024,1024]
    const long long off6 = off5 + (long long)BB * TT * TT; // score_ksh [16384,512]

    float* o_idx  = out + off0;
    float* o_vpw  = out + off1;
    float* o_vph  = out + off2;
    float* o_vpss = out + off3;
    float* o_vpsh = out + off4;
    float* o_kss  = out + off5;
    float* o_ksh  = out + off6;

    // Scratch in ws: ksn (16 MB) + 3 small tables (1.5 MB)
    float* ksn    = (float*)d_ws;                 // [16384,256]
    float* keys_n = ksn + (long long)BT * DD;     // [512,256]
    float* vp_n   = keys_n + (long long)NE * DD;  // [512,256]
    float* vpnT   = vp_n + (long long)NE * DD;    // [256,512]

    // Big intermediates borrow d_out regions that are overwritten later:
    float* w_scr   = o_kss;   // softmax weights [16384,512]; consumed before kss GEMM
    float* raw_scr = o_vpss;  // un-normalized vparams_w [16384,256]; consumed before vpss GEMM

    // 1) normalizations
    l2norm_rows<<<BT, 256, 0, stream>>>(key_soft, ksn);
    l2norm_rows<<<NE, 256, 0, stream>>>(keys, keys_n);
    l2norm_rows<<<NE, 256, 0, stream>>>(vparams, vp_n);
    transpose_kern<<<(NE * DD + 255) / 256, 256, 0, stream>>>(vp_n, vpnT, NE, DD);

    // 2) score_ksh = ksn @ keys_n^T   [16384, 512]
    gemm_nt<<<dim3(NE / 128, BT / 128, 1), 256, 0, stream>>>(
        ksn, keys_n, o_ksh, BT, NE, DD, 0, 0, 0);

    // 3) argmax + softmax
    softmax_argmax<<<BT, 256, 0, stream>>>(o_ksh, o_idx, w_scr);

    // 4) raw vparams_w = w @ vp_n  == w[M,512] * vpnT[256,512]^T
    gemm_nt<<<dim3(DD / 128, BT / 128, 1), 256, 0, stream>>>(
        w_scr, vpnT, raw_scr, BT, DD, NE, 0, 0, 0);

    // 5) normalize + hard gather
    vpw_finish<<<BT, 256, 0, stream>>>(raw_scr, o_idx, vp_n, o_vpw, o_vph);

    // 6) score_kss = ksn @ ksn^T per batch (overwrites w_scr region — already consumed)
    gemm_nt<<<dim3(TT / 128, TT / 128, BB), 256, 0, stream>>>(
        ksn, ksn, o_kss, TT, TT, DD,
        (long long)TT * DD, (long long)TT * DD, (long long)TT * TT);

    // 7) score_vpss = vpw @ vpw^T per batch (overwrites raw_scr region — already consumed)
    gemm_nt<<<dim3(TT / 128, TT / 128, BB), 256, 0, stream>>>(
        o_vpw, o_vpw, o_vpss, TT, TT, DD,
        (long long)TT * DD, (long long)TT * DD, (long long)TT * TT);

    // 8) score_vpsh = vpw @ vp_n^T   [16384, 512]
    gemm_nt<<<dim3(NE / 128, BT / 128, 1), 256, 0, stream>>>(
        o_vpw, vp_n, o_vpsh, BT, NE, DD, 0, 0, 0);
}

// Round 2
// 387.400 us; speedup vs baseline: 1.6868x; 1.6868x over previous
//
#include <hip/hip_runtime.h>
#include <hip/hip_bf16.h>

// Problem constants
#define BB 16
#define TT 1024
#define DD 256
#define NE 512
#define BT 16384   // BB*TT

typedef unsigned short ushort_t;
typedef __attribute__((ext_vector_type(8))) short bf16x8;
typedef __attribute__((ext_vector_type(4))) float f32x4;

#define AS_GLOBAL __attribute__((address_space(1)))
#define AS_SHARED __attribute__((address_space(3)))

static __device__ __forceinline__ ushort_t f2bf(float f) {
    union { float f; unsigned u; } x; x.f = f;
    unsigned r = x.u + 0x7fffu + ((x.u >> 16) & 1u);   // RNE
    return (ushort_t)(r >> 16);
}

// ---------------------------------------------------------------------------
// Row-wise L2 normalize, cols == 256. Optional bf16 copy of the output.
// ---------------------------------------------------------------------------
__global__ __launch_bounds__(256) void l2norm_dual(const float* __restrict__ in,
                                                   float* __restrict__ out,
                                                   ushort_t* __restrict__ out_bf) {
    const int row = blockIdx.x;
    const long long base = (long long)row * DD;
    const int t = threadIdx.x;
    float v = in[base + t];
    float ss = v * v;
    #pragma unroll
    for (int off = 32; off > 0; off >>= 1) ss += __shfl_down(ss, off, 64);
    __shared__ float partial[4];
    const int wave = t >> 6, lane = t & 63;
    if (lane == 0) partial[wave] = ss;
    __syncthreads();
    __shared__ float s_inv;
    if (t == 0) {
        float tot = partial[0] + partial[1] + partial[2] + partial[3];
        s_inv = 1.0f / fmaxf(sqrtf(tot), 1e-12f);
    }
    __syncthreads();
    const float r = v * s_inv;
    out[base + t] = r;
    if (out_bf) out_bf[base + t] = f2bf(r);
}

// ---------------------------------------------------------------------------
// Transpose fp32 [rows, cols] -> bf16 [cols, rows]
// ---------------------------------------------------------------------------
__global__ void transpose_bf(const float* __restrict__ in, ushort_t* __restrict__ out,
                             int rows, int cols) {
    int idx = blockIdx.x * blockDim.x + threadIdx.x;
    if (idx < rows * cols) {
        int r = idx / cols, c = idx - r * cols;
        out[(long long)c * rows + r] = f2bf(in[idx]);
    }
}

// ---------------------------------------------------------------------------
// fp32 vector GEMM: C[M,N] = A[M,K] * B[N,K]^T (only for score_ksh / argmax)
// ---------------------------------------------------------------------------
__global__ __launch_bounds__(256) void gemm_nt(const float* __restrict__ A,
                                               const float* __restrict__ Bm,
                                               float* __restrict__ C,
                                               int M, int N, int K) {
    const int bm = blockIdx.y * 128;
    const int bn = blockIdx.x * 128;

    __shared__ float As[16][132];
    __shared__ float Bs[16][132];

    const int tid = threadIdx.x;
    const int tx = tid & 15;
    const int ty = tid >> 4;
    const int r  = tid >> 2;
    const int c4 = tid & 3;

    float acc[8][8] = {};

    for (int k0 = 0; k0 < K; k0 += 16) {
        #pragma unroll
        for (int i = 0; i < 2; ++i) {
            const int rr = r + i * 64;
            float4 va = *(const float4*)(A + (long long)(bm + rr) * K + k0 + c4 * 4);
            As[c4 * 4 + 0][rr] = va.x;
            As[c4 * 4 + 1][rr] = va.y;
            As[c4 * 4 + 2][rr] = va.z;
            As[c4 * 4 + 3][rr] = va.w;
            float4 vb = *(const float4*)(Bm + (long long)(bn + rr) * K + k0 + c4 * 4);
            Bs[c4 * 4 + 0][rr] = vb.x;
            Bs[c4 * 4 + 1][rr] = vb.y;
            Bs[c4 * 4 + 2][rr] = vb.z;
            Bs[c4 * 4 + 3][rr] = vb.w;
        }
        __syncthreads();
        #pragma unroll
        for (int k = 0; k < 16; ++k) {
            float a[8], b[8];
            *(float4*)&a[0] = *(const float4*)&As[k][ty * 8];
            *(float4*)&a[4] = *(const float4*)&As[k][ty * 8 + 4];
            *(float4*)&b[0] = *(const float4*)&Bs[k][tx * 8];
            *(float4*)&b[4] = *(const float4*)&Bs[k][tx * 8 + 4];
            #pragma unroll
            for (int i = 0; i < 8; ++i)
                #pragma unroll
                for (int j = 0; j < 8; ++j)
                    acc[i][j] = fmaf(a[i], b[j], acc[i][j]);
        }
        __syncthreads();
    }

    #pragma unroll
    for (int i = 0; i < 8; ++i) {
        float* dst = C + (long long)(bm + ty * 8 + i) * N + bn + tx * 8;
        *(float4*)dst       = make_float4(acc[i][0], acc[i][1], acc[i][2], acc[i][3]);
        *(float4*)(dst + 4) = make_float4(acc[i][4], acc[i][5], acc[i][6], acc[i][7]);
    }
}

// ---------------------------------------------------------------------------
// bf16 MFMA GEMM: C[M,N]fp32 = A[M,K]bf16 * B[N,K]bf16^T
// 128x128 tile, BK=32, 256 threads = 4 waves, each wave 64x64 (4x4 MFMA tiles).
// global -> LDS via global_load_lds width 16. M,N %128==0, K %32==0.
// ---------------------------------------------------------------------------
__global__ __launch_bounds__(256) void gemm_bf16_nt(const ushort_t* __restrict__ A,
                                                    const ushort_t* __restrict__ Bm,
                                                    float* __restrict__ C,
                                                    int M, int N, int K,
                                                    long long sA, long long sB, long long sC) {
    A  += sA * blockIdx.z;
    Bm += sB * blockIdx.z;
    C  += sC * blockIdx.z;
    const int bm = blockIdx.y * 128;
    const int bn = blockIdx.x * 128;

    __shared__ ushort_t As[128 * 32];   // [row][k], k contiguous (global_load_lds order)
    __shared__ ushort_t Bs[128 * 32];

    const int tid = threadIdx.x;
    const int wv = tid >> 6;            // wave 0..3
    const int ln = tid & 63;

    // staging lanes: 16 rows x 4 chunks of 8 bf16 per instruction
    const int srow   = ln >> 2;         // 0..15
    const int schunk = (ln & 3) * 8;    // 0,8,16,24

    // MFMA fragment coords
    const int wm = (wv >> 1) * 64;      // wave m-offset in tile
    const int wn = (wv & 1) * 64;      // wave n-offset
    const int fr = ln & 15;             // row within 16-tile
    const int fq = (ln >> 4) * 8;       // k-offset within 32

    f32x4 acc[4][4] = {};

    for (int k0 = 0; k0 < K; k0 += 32) {
        #pragma unroll
        for (int t = 0; t < 2; ++t) {
            const int ra = wv * 32 + t * 16;   // local row base (wave-uniform)
            const ushort_t* ga = A + (long long)(bm + ra + srow) * K + k0 + schunk;
            __builtin_amdgcn_global_load_lds((const AS_GLOBAL void*)ga,
                                             (AS_SHARED void*)&As[ra * 32], 16, 0, 0);
            const ushort_t* gb = Bm + (long long)(bn + ra + srow) * K + k0 + schunk;
            __builtin_amdgcn_global_load_lds((const AS_GLOBAL void*)gb,
                                             (AS_SHARED void*)&Bs[ra * 32], 16, 0, 0);
        }
        __syncthreads();

        bf16x8 af[4], bfr[4];
        #pragma unroll
        for (int i = 0; i < 4; ++i)
            af[i] = *(const bf16x8*)&As[(wm + i * 16 + fr) * 32 + fq];
        #pragma unroll
        for (int j = 0; j < 4; ++j)
            bfr[j] = *(const bf16x8*)&Bs[(wn + j * 16 + fr) * 32 + fq];
        #pragma unroll
        for (int i = 0; i < 4; ++i)
            #pragma unroll
            for (int j = 0; j < 4; ++j)
                acc[i][j] = __builtin_amdgcn_mfma_f32_16x16x32_bf16(af[i], bfr[j], acc[i][j], 0, 0, 0);
        __syncthreads();
    }

    // C/D layout: col = lane&15, row = (lane>>4)*4 + reg
    const int col  = ln & 15;
    const int qrow = (ln >> 4) * 4;
    #pragma unroll
    for (int i = 0; i < 4; ++i)
        #pragma unroll
        for (int j = 0; j < 4; ++j) {
            #pragma unroll
            for (int r = 0; r < 4; ++r)
                C[(long long)(bm + wm + i * 16 + qrow + r) * N + bn + wn + j * 16 + col] = acc[i][j][r];
        }
}

// ---------------------------------------------------------------------------
// Per row of score_ksh [BT, NE]: argmax (as float) + softmax weights (bf16).
// ---------------------------------------------------------------------------
__global__ __launch_bounds__(256) void softmax_argmax(const float* __restrict__ S,
                                                      float* __restrict__ idx_out,
                                                      ushort_t* __restrict__ W) {
    const int row = blockIdx.x;
    const long long base = (long long)row * NE;
    const int t = threadIdx.x;
    const float v0 = S[base + t];
    const float v1 = S[base + t + 256];

    float bv; int bi;
    if (v1 > v0) { bv = v1; bi = t + 256; } else { bv = v0; bi = t; }
    #pragma unroll
    for (int off = 32; off > 0; off >>= 1) {
        float ov = __shfl_down(bv, off, 64);
        int   oi = __shfl_down(bi, off, 64);
        if (ov > bv || (ov == bv && oi < bi)) { bv = ov; bi = oi; }
    }
    __shared__ float pv[4];
    __shared__ int   pi[4];
    const int wave = t >> 6, lane = t & 63;
    if (lane == 0) { pv[wave] = bv; pi[wave] = bi; }
    __syncthreads();
    __shared__ float s_max;
    __shared__ int   s_idx;
    if (t == 0) {
        bv = pv[0]; bi = pi[0];
        #pragma unroll
        for (int k = 1; k < 4; ++k)
            if (pv[k] > bv || (pv[k] == bv && pi[k] < bi)) { bv = pv[k]; bi = pi[k]; }
        s_max = bv; s_idx = bi;
    }
    __syncthreads();
    const float m = s_max;
    const float e0 = expf(v0 - m);
    const float e1 = expf(v1 - m);
    float ssum = e0 + e1;
    #pragma unroll
    for (int off = 32; off > 0; off >>= 1) ssum += __shfl_down(ssum, off, 64);
    __shared__ float ps[4];
    if (lane == 0) ps[wave] = ssum;
    __syncthreads();
    __shared__ float s_sum;
    if (t == 0) s_sum = ps[0] + ps[1] + ps[2] + ps[3];
    __syncthreads();
    const float inv = 1.0f / s_sum;
    W[base + t]       = f2bf(e0 * inv);
    W[base + t + 256] = f2bf(e1 * inv);
    if (t == 0) idx_out[row] = (float)s_idx;
}

// ---------------------------------------------------------------------------
// Normalize raw vparams_w rows -> vpw fp32 + bf16; gather vp_norm[idx] -> vph.
// ---------------------------------------------------------------------------
__global__ __launch_bounds__(256) void vpw_finish(const float* __restrict__ raw,
                                                  const float* __restrict__ idxf,
                                                  const float* __restrict__ vp_norm,
                                                  float* __restrict__ vpw,
                                                  ushort_t* __restrict__ vpw_bf,
                                                  float* __restrict__ vph) {
    const int row = blockIdx.x;
    const long long base = (long long)row * DD;
    const int t = threadIdx.x;
    const float v = raw[base + t];
    float ss = v * v;
    #pragma unroll
    for (int off = 32; off > 0; off >>= 1) ss += __shfl_down(ss, off, 64);
    __shared__ float partial[4];
    const int wave = t >> 6, lane = t & 63;
    if (lane == 0) partial[wave] = ss;
    __syncthreads();
    __shared__ float s_inv;
    if (t == 0) {
        float tot = partial[0] + partial[1] + partial[2] + partial[3];
        s_inv = 1.0f / fmaxf(sqrtf(tot), 1e-12f);
    }
    __syncthreads();
    const float r = v * s_inv;
    vpw[base + t] = r;
    vpw_bf[base + t] = f2bf(r);
    const int idx = (int)idxf[row];
    vph[base + t] = vp_norm[(long long)idx * DD + t];
}

// ---------------------------------------------------------------------------
extern "C" void kernel_launch(void* const* d_in, const int* in_sizes, int n_in,
                              void* d_out, int out_size, void* d_ws, size_t ws_size,
                              hipStream_t stream) {
    const float* key_soft = (const float*)d_in[0];   // [16,1024,256]
    const float* keys     = (const float*)d_in[1];   // [512,256]
    const float* vparams  = (const float*)d_in[2];   // [512,256]
    float* out = (float*)d_out;

    // Output layout (flat, return order)
    const long long off0 = 0;                               // encoding_indices [16384]
    const long long off1 = off0 + BT;                       // vparams_w  [16384,256]
    const long long off2 = off1 + (long long)BT * DD;       // vparams_hard
    const long long off3 = off2 + (long long)BT * DD;       // score_vpss [16,1024,1024]
    const long long off4 = off3 + (long long)BB * TT * TT;  // score_vpsh [16384,512]
    const long long off5 = off4 + (long long)BT * NE;       // score_kss [16,1024,1024]
    const long long off6 = off5 + (long long)BB * TT * TT;  // score_ksh [16384,512]

    float* o_idx  = out + off0;
    float* o_vpw  = out + off1;
    float* o_vph  = out + off2;
    float* o_vpss = out + off3;
    float* o_vpsh = out + off4;
    float* o_kss  = out + off5;
    float* o_ksh  = out + off6;

    // ws scratch (~9.5 MB, well under the known-good 17.7 MB footprint)
    float*    keys_n  = (float*)d_ws;                          // [512,256] fp32
    float*    vp_n    = keys_n + (long long)NE * DD;           // [512,256] fp32
    ushort_t* vp_n_bf = (ushort_t*)(vp_n + (long long)NE * DD);// [512,256] bf16
    ushort_t* vpnT_bf = vp_n_bf + (long long)NE * DD;          // [256,512] bf16
    ushort_t* vpw_bf  = vpnT_bf + (long long)DD * NE;          // [16384,256] bf16

    // Borrowed d_out regions (each consumed before its region is overwritten):
    float*    ksn     = o_kss;                                  // [16384,256] fp32 (dead after score_ksh gemm; o_kss written later)
    ushort_t* ksn_bf  = (ushort_t*)o_vpsh;                      // [16384,256] bf16 (dead after kss gemm; o_vpsh written last)
    float*    raw_scr = o_vpss;                                 // [16384,256] fp32 raw vparams_w
    ushort_t* w_bf    = (ushort_t*)(o_vpss + (long long)BT * DD); // [16384,512] bf16 softmax weights, +16MB into vpss region

    // 1) normalizations (+ bf16 copies)
    l2norm_dual<<<BT, 256, 0, stream>>>(key_soft, ksn, ksn_bf);
    l2norm_dual<<<NE, 256, 0, stream>>>(keys, keys_n, (ushort_t*)nullptr);
    l2norm_dual<<<NE, 256, 0, stream>>>(vparams, vp_n, vp_n_bf);
    transpose_bf<<<(NE * DD + 255) / 256, 256, 0, stream>>>(vp_n, vpnT_bf, NE, DD);

    // 2) score_ksh = ksn @ keys_n^T (fp32 — feeds argmax; bf16 would flip near-ties)
    gemm_nt<<<dim3(NE / 128, BT / 128, 1), 256, 0, stream>>>(
        ksn, keys_n, o_ksh, BT, NE, DD);

    // 3) argmax + softmax -> w_bf
    softmax_argmax<<<BT, 256, 0, stream>>>(o_ksh, o_idx, w_bf);

    // 4) raw vparams_w = w @ vp_n   (A=w_bf [BT,512], B=vpnT_bf [256,512])
    gemm_bf16_nt<<<dim3(DD / 128, BT / 128, 1), 256, 0, stream>>>(
        w_bf, vpnT_bf, raw_scr, BT, DD, NE, 0, 0, 0);

    // 5) score_kss = ksn_bf @ ksn_bf^T per batch (overwrites ksn fp32 — dead)
    gemm_bf16_nt<<<dim3(TT / 128, TT / 128, BB), 256, 0, stream>>>(
        ksn_bf, ksn_bf, o_kss, TT, TT, DD,
        (long long)TT * DD, (long long)TT * DD, (long long)TT * TT);

    // 6) normalize + hard gather (+ vpw bf16 into ws)
    vpw_finish<<<BT, 256, 0, stream>>>(raw_scr, o_idx, vp_n, o_vpw, vpw_bf, o_vph);

    // 7) score_vpss = vpw @ vpw^T per batch (overwrites raw_scr + w_bf — both dead)
    gemm_bf16_nt<<<dim3(TT / 128, TT / 128, BB), 256, 0, stream>>>(
        vpw_bf, vpw_bf, o_vpss, TT, TT, DD,
        (long long)TT * DD, (long long)TT * DD, (long long)TT * TT);

    // 8) score_vpsh = vpw @ vp_n^T (overwrites ksn_bf — dead)
    gemm_bf16_nt<<<dim3(NE / 128, BT / 128, 1), 256, 0, stream>>>(
        vpw_bf, vp_n_bf, o_vpsh, BT, NE, DD, 0, 0, 0);
}